// Round 1
// baseline (1259.728 us; speedup 1.0000x reference)
//
#include <hip/hip_runtime.h>
#include <hip/hip_bf16.h>
#include <cstdint>
#include <cstddef>

#define HWIMG 13824   // H*W = 96*144
#define NTOK  110592  // B*H*W
#define CDIM  512

typedef float  floatx4  __attribute__((ext_vector_type(4)));
typedef __bf16 bf16x8   __attribute__((ext_vector_type(8)));
typedef unsigned short ushortx8 __attribute__((ext_vector_type(8)));

__device__ __forceinline__ unsigned short f2bf(float f) {
  unsigned int u = __float_as_uint(f);
  u += 0x7FFFu + ((u >> 16) & 1u);   // round-to-nearest-even
  return (unsigned short)(u >> 16);
}

#define GLL16(g, l)                                                                \
  __builtin_amdgcn_global_load_lds((const __attribute__((address_space(1))) void*)(g), \
                                   (__attribute__((address_space(3))) void*)(l), 16, 0, 0)

// ---------------------------------------------------------------------------
// K0: memory fp32 -> bf16 (row-major [m][d]) and transposed bf16 [d][m]
// ---------------------------------------------------------------------------
__global__ __launch_bounds__(256) void convert_mem_kernel(
    const float* __restrict__ mem, unsigned short* __restrict__ membf,
    unsigned short* __restrict__ memTbf) {
  int g = blockIdx.x * 256 + threadIdx.x;  // 0 .. 262143
  int m = g >> 9, d = g & 511;
  unsigned short b = f2bf(mem[g]);
  membf[g] = b;
  memTbf[d * 512 + m] = b;
}

// ---------------------------------------------------------------------------
// K1: L2-normalize over channel dim + transpose [B,C,H,W] -> qbf [N,512] bf16
// One block = 64 tokens (one b, consecutive r = h*W+w; 64 | 13824).
// ---------------------------------------------------------------------------
__global__ __launch_bounds__(256) void normalize_kernel(
    const float* __restrict__ qs, unsigned short* __restrict__ qbf) {
  __shared__ float red[4][64];
  __shared__ float inv[64];
  __shared__ float tile[64][65];  // +1 pad: conflict-free transposed reads
  const int t = threadIdx.x;
  const int n0 = blockIdx.x * 64;
  const int b = n0 / HWIMG;
  const int r0 = n0 % HWIMG;
  const float* base = qs + (size_t)b * 512 * HWIMG + r0;
  const int tok = t & 63, cp = t >> 6;

  float ssq = 0.f;
  for (int c = cp; c < 512; c += 4) {
    float x = base[(size_t)c * HWIMG + tok];   // coalesced: lanes across tok
    ssq += x * x;
  }
  red[cp][tok] = ssq;
  __syncthreads();
  if (t < 64) {
    float s = red[0][t] + red[1][t] + red[2][t] + red[3][t];
    inv[t] = 1.0f / fmaxf(sqrtf(s), 1e-12f);   // F.normalize eps semantics
  }
  __syncthreads();

  for (int cc = 0; cc < 8; cc++) {             // 8 chunks of 64 channels
#pragma unroll
    for (int i = 0; i < 16; i++) {
      int cl = (t >> 6) + i * 4;
      tile[cl][tok] = base[(size_t)(cc * 64 + cl) * HWIMG + tok];  // coalesced
    }
    __syncthreads();
    const int c_out = t & 63;
    const int tg = t >> 6;
#pragma unroll
    for (int i = 0; i < 16; i++) {
      int tk = tg * 16 + i;
      float v = tile[c_out][tk] * inv[tk];
      qbf[(size_t)(n0 + tk) * 512 + cc * 64 + c_out] = f2bf(v);    // coalesced in c
    }
    __syncthreads();
  }
}

// ---------------------------------------------------------------------------
// GEMM core layout (both GEMMs): BM=BN=128, BK=32, 256 thr = 4 waves (2x2 of 64x64).
// LDS tiles stored fragment-contiguous: 16B chunk index = g*64 + lane where
// g = m/16 group; wave reads chunk (g*64+lane) -> linear, conflict-free, and
// global_load_lds writes linear lane*16 -> satisfies wave-uniform-base rule.
// A[m][k], B[n][k] both row-major-in-k (NT gemm). mfma_f32_16x16x32_bf16:
// A[m=lane&15][k=quad*8+j], B likewise, D: col=lane&15, row=quad*4+reg.
// ---------------------------------------------------------------------------
#define GEMM_PROLOGUE(Aptr, Bptr)                                               \
  __shared__ unsigned short Alds[128 * 32];                                     \
  __shared__ unsigned short Blds[128 * 32];                                     \
  const int t = threadIdx.x;                                                    \
  const int lane = t & 63;                                                      \
  const int wid = t >> 6;                                                       \
  const int n0 = blockIdx.x * 128;                                              \
  const int m0 = blockIdx.y * 128;                                              \
  floatx4 acc[4][4];                                                            \
  {                                                                             \
    floatx4 z = {0.f, 0.f, 0.f, 0.f};                                           \
    for (int i = 0; i < 4; i++)                                                 \
      for (int j = 0; j < 4; j++) acc[i][j] = z;                                \
  }                                                                             \
  const int cid0 = t, cid1 = t + 256;                                           \
  const int row0 = ((cid0 >> 6) << 4) | (cid0 & 15);                            \
  const int row1 = ((cid1 >> 6) << 4) | (cid1 & 15);                            \
  const int qb0 = ((cid0 >> 4) & 3) << 4;                                       \
  const int qb1 = ((cid1 >> 4) & 3) << 4;                                       \
  const char* gA0 = (const char*)(Aptr) + (size_t)(n0 + row0) * 1024 + qb0;     \
  const char* gA1 = (const char*)(Aptr) + (size_t)(n0 + row1) * 1024 + qb1;     \
  const char* gB0 = (const char*)(Bptr) + (size_t)(m0 + row0) * 1024 + qb0;     \
  const char* gB1 = (const char*)(Bptr) + (size_t)(m0 + row1) * 1024 + qb1;     \
  char* lA0 = (char*)Alds + cid0 * 16;                                          \
  char* lA1 = (char*)Alds + cid1 * 16;                                          \
  char* lB0 = (char*)Blds + cid0 * 16;                                          \
  char* lB1 = (char*)Blds + cid1 * 16;                                          \
  const int am = (wid & 1) * 4;                                                 \
  const int bn = (wid >> 1) * 4;                                                \
  for (int kb = 0; kb < 1024; kb += 64) { /* byte offset along K=512 bf16 */    \
    GLL16(gA0 + kb, lA0);                                                       \
    GLL16(gA1 + kb, lA1);                                                       \
    GLL16(gB0 + kb, lB0);                                                       \
    GLL16(gB1 + kb, lB1);                                                       \
    asm volatile("s_waitcnt vmcnt(0)" ::: "memory");                            \
    __syncthreads();                                                            \
    bf16x8 af[4], bfv[4];                                                       \
    for (int i = 0; i < 4; i++)                                                 \
      af[i] = *(const bf16x8*)&Alds[((am + i) * 64 + lane) * 8];                \
    for (int j = 0; j < 4; j++)                                                 \
      bfv[j] = *(const bf16x8*)&Blds[((bn + j) * 64 + lane) * 8];               \
    for (int i = 0; i < 4; i++)                                                 \
      for (int j = 0; j < 4; j++)                                               \
        acc[i][j] =                                                             \
            __builtin_amdgcn_mfma_f32_16x16x32_bf16(af[i], bfv[j], acc[i][j], 0, 0, 0); \
    __syncthreads();                                                            \
  }

// GEMM1: E = exp(qbf . membf^T); accumulate rowsum/colsum of E via atomics.
__global__ __launch_bounds__(256, 2) void gemm1_kernel(
    const unsigned short* __restrict__ A, const unsigned short* __restrict__ Bm,
    float* __restrict__ E, float* __restrict__ colsum, float* __restrict__ rowsum) {
  __shared__ float cs_lds[128];
  __shared__ float rs_lds[128];
  if (threadIdx.x < 128) { cs_lds[threadIdx.x] = 0.f; rs_lds[threadIdx.x] = 0.f; }
  GEMM_PROLOGUE(A, Bm)
  const int quad = lane >> 4, li = lane & 15;
  const int wm = (wid & 1) * 64, wn = (wid >> 1) * 64;
  float cp[4] = {0.f, 0.f, 0.f, 0.f};
#pragma unroll
  for (int i = 0; i < 4; i++) {
#pragma unroll
    for (int r = 0; r < 4; r++) {
      float rowacc = 0.f;
      const int row = n0 + wm + i * 16 + quad * 4 + r;
#pragma unroll
      for (int j = 0; j < 4; j++) {
        float e = __expf(acc[i][j][r]);   // |score|<=~1.1 -> no max shift needed
        const int col = m0 + wn + j * 16 + li;
        E[(size_t)row * 512 + col] = e;
        cp[j] += e;
        rowacc += e;
      }
      rowacc += __shfl_xor(rowacc, 1, 64);
      rowacc += __shfl_xor(rowacc, 2, 64);
      rowacc += __shfl_xor(rowacc, 4, 64);
      rowacc += __shfl_xor(rowacc, 8, 64);
      if (li == 0) atomicAdd(&rs_lds[wm + i * 16 + quad * 4 + r], rowacc);
    }
  }
#pragma unroll
  for (int j = 0; j < 4; j++) {
    float c = cp[j];
    c += __shfl_xor(c, 16, 64);
    c += __shfl_xor(c, 32, 64);
    if (lane < 16) atomicAdd(&cs_lds[wn + j * 16 + li], c);
  }
  __syncthreads();
  if (t < 128) {
    atomicAdd(&rowsum[n0 + t], rs_lds[t]);
    atomicAdd(&colsum[m0 + t], cs_lds[t]);
  }
}

// GEMM2: out0[b,d,h,w] = (P . memT^T)[n,d]; acc regs are 4 consecutive tokens
// -> float4 store directly into the [B,D,H,W] layout.
__global__ __launch_bounds__(256, 2) void gemm2_kernel(
    const unsigned short* __restrict__ P, const unsigned short* __restrict__ BmT,
    float* __restrict__ out0) {
  GEMM_PROLOGUE(P, BmT)
  const int quad = lane >> 4, li = lane & 15;
  const int wm = (wid & 1) * 64, wn = (wid >> 1) * 64;
  const int bimg = n0 / HWIMG;   // 128 | 13824 -> block never straddles b
  const int r0 = n0 % HWIMG;
#pragma unroll
  for (int i = 0; i < 4; i++) {
    const int rb = r0 + wm + i * 16 + quad * 4;
#pragma unroll
    for (int j = 0; j < 4; j++) {
      const int col = m0 + wn + j * 16 + li;  // = d
      *(floatx4*)&out0[(size_t)(bimg * 512 + col) * HWIMG + rb] = acc[i][j];
    }
  }
}

// ---------------------------------------------------------------------------
// K4: out1 = E/colsum (in place over E), out2 = E/rowsum, pbf = bf16(out2).
// One wave per 64 rows; lane owns 8 fixed columns.
// ---------------------------------------------------------------------------
__global__ __launch_bounds__(256) void finalize_kernel(
    float* __restrict__ E, const float* __restrict__ colsum,
    const float* __restrict__ rowsum, float* __restrict__ out2,
    unsigned short* __restrict__ pbf) {
  const int t = threadIdx.x;
  const int lane = t & 63, wid = t >> 6;
  const int wg = blockIdx.x * 4 + wid;     // 0..1727
  const int c0 = lane * 8;
  floatx4 one = {1.f, 1.f, 1.f, 1.f};
  floatx4 rc0 = one / *(const floatx4*)&colsum[c0];
  floatx4 rc1 = one / *(const floatx4*)&colsum[c0 + 4];
  for (int it = 0; it < 64; it++) {
    const int row = wg * 64 + it;
    const size_t off = (size_t)row * 512 + c0;
    floatx4 e0 = *(const floatx4*)&E[off];
    floatx4 e1 = *(const floatx4*)&E[off + 4];
    float rr = 1.0f / rowsum[row];
    floatx4 o2a = e0 * rr, o2b = e1 * rr;
    *(floatx4*)&E[off]     = e0 * rc0;   // out1 in place
    *(floatx4*)&E[off + 4] = e1 * rc1;
    *(floatx4*)&out2[off]     = o2a;
    *(floatx4*)&out2[off + 4] = o2b;
    ushortx8 p;
    p[0] = f2bf(o2a[0]); p[1] = f2bf(o2a[1]); p[2] = f2bf(o2a[2]); p[3] = f2bf(o2a[3]);
    p[4] = f2bf(o2b[0]); p[5] = f2bf(o2b[1]); p[6] = f2bf(o2b[2]); p[7] = f2bf(o2b[3]);
    *(ushortx8*)&pbf[off] = p;
  }
}

// ---------------------------------------------------------------------------
extern "C" void kernel_launch(void* const* d_in, const int* in_sizes, int n_in,
                              void* d_out, int out_size, void* d_ws, size_t ws_size,
                              hipStream_t stream) {
  const float* qs  = (const float*)d_in[0];   // [8,512,96,144] fp32
  const float* mem = (const float*)d_in[1];   // [512,512] fp32 (pre-normalized)

  float* out0 = (float*)d_out;                       // updated_query [8,512,96,144]
  float* out1 = out0 + (size_t)NTOK * 512;           // col-softmax; holds E first
  float* out2 = out1 + (size_t)NTOK * 512;           // row-softmax

  char* ws = (char*)d_ws;
  unsigned short* qbf    = (unsigned short*)ws;                    // 113,246,208 B
  unsigned short* pbf    = qbf;                                    // reuse: qbf dead after gemm1
  unsigned short* membf  = (unsigned short*)(ws + 113246208);      // 524,288 B
  unsigned short* memTbf = (unsigned short*)(ws + 113770496);      // 524,288 B
  float* colsum          = (float*)(ws + 114294784);               // 2,048 B
  float* rowsum          = (float*)(ws + 114296832);               // 442,368 B

  hipMemsetAsync(colsum, 0, 2048 + 442368, stream);  // ws re-poisoned each call
  convert_mem_kernel<<<1024, 256, 0, stream>>>(mem, membf, memTbf);
  normalize_kernel<<<NTOK / 64, 256, 0, stream>>>(qs, qbf);
  gemm1_kernel<<<dim3(NTOK / 128, 4), 256, 0, stream>>>(qbf, membf, out1, colsum, rowsum);
  finalize_kernel<<<NTOK / 256, 256, 0, stream>>>(out1, colsum, rowsum, out2, pbf);
  gemm2_kernel<<<dim3(NTOK / 128, 4), 256, 0, stream>>>(pbf, memTbf, out0);
}